// Round 17
// baseline (169.173 us; speedup 1.0000x reference)
//
#include <hip/hip_runtime.h>
#include <hip/hip_bf16.h>

#define IMG    384
#define CDIM   60
#define NWIN   48
#define WNUM   (NWIN * NWIN)   // 2304

typedef short  bf16x8 __attribute__((ext_vector_type(8)));
typedef float  f32x4  __attribute__((ext_vector_type(4)));
union Frag { int4 i4; bf16x8 b8; };

#define MFMA(a, b, c) __builtin_amdgcn_mfma_f32_16x16x32_bf16((a), (b), (c), 0, 0, 0)

// d_ws layout
#define WS_QKVF  0        // 12 qk mtiles x 2 ks x 1KB = 24576 (A-frags; Wq pre-scaled)
#define WS_VF    24576    // 6 heads x 2 ks x 1KB      = 12288 (B-frags)
#define WS_PROJF 36864    // 4 x 2 x 1KB               = 8192  (A-frags)
#define WS_BIASC 45056    // [6][4][4][64] f32x4 C-frag bias (prescaled log2e) = 98304

#define SCALE_L2E (0.31622776601683794f * 1.4426950408889634f)  // 1/sqrt(10)*log2(e)
#define MASK_L2E  144.26950408889634f                            // 100*log2(e)
#define LOG2E     1.4426950408889634f
#define ONESBF2   0x3F803F80                                     // bf16{1.0,1.0}

__device__ __forceinline__ unsigned short f2bf(float f) {
    unsigned int u = __float_as_uint(f);
    unsigned int r = u + 0x7fffu + ((u >> 16) & 1u);
    return (unsigned short)(r >> 16);
}
__device__ __forceinline__ unsigned int pk2bf(float a, float b) {
    union { __hip_bfloat162 h; unsigned int u; } c;
    c.h = __float22bfloat162_rn(float2{a, b});
    return c.u;
}
__device__ __forceinline__ int regionOf(int x) {
    return (x < IMG - 8) ? 0 : ((x < IMG - 4) ? 1 : 2);
}
// all LDS buffers: 128B rows, XOR swizzle on byte bit 4 keyed by row&7
__device__ __forceinline__ int swz(int row, int byteoff) {
    return (row * 128 + byteoff) ^ ((row & 7) << 4);
}
// q/k packed row: [6 heads x 16B (d0-7)] at h*16, [6 x 4B (d8,d9)] at 96+h*4
__device__ __forceinline__ int4 qk_frag(const unsigned short* buf, int tok, int h, int g) {
    if (g == 0) return *(const int4*)((const char*)buf + swz(tok, h * 16));
    if (g == 1) {
        int v = *(const int*)((const char*)buf + swz(tok, 96 + h * 4));
        return int4{v, 0, 0, 0};
    }
    return int4{0, 0, 0, 0};
}

// ---------------------------------------------------------------------------
// Attention head-group: MC m-tiles of head h. Full-width P slab (R12):
// write all 4 P-pairs -> one wait -> 2 b128 reads -> both PV MFMAs.
// Denominator ones-rows built in registers (lanes l15>=10) -> single bpermute.
// Bias enters as the QK MFMA C-initializer.
// ---------------------------------------------------------------------------
template<int MC>
__device__ __forceinline__ void attn_group(
    int h, int m0, const Frag (&kb)[4],
    int lane, int l15, int g, int dl, bool boundary, int wh, int ww,
    const unsigned short* qall, const unsigned short* vall,
    unsigned short* osb,            // = kall region (overlay)
    char* slab, int prow, const float4* biasC)
{
    Frag va[2];
    const bool vre = (l15 < 10);
    int vrow = h * 10 + (vre ? l15 : 0);
    #pragma unroll
    for (int ks = 0; ks < 2; ++ks) {
        int4 r = *(const int4*)((const char*)vall + swz(vrow, ks * 64 + g * 16));
        va[ks].i4 = vre ? r : int4{ONESBF2, ONESBF2, ONESBF2, ONESBF2};
    }

    #pragma unroll
    for (int mm = 0; mm < MC; ++mm) {
        int m = m0 + mm;
        int i_tok = m * 16 + l15;
        Frag qa;
        qa.i4 = qk_frag(qall, i_tok, h, g);

        // S^T with C = bias^T (prescaled by log2e; q prescaled by scale*log2e)
        const float4* bc = biasC + (h * 16 + m * 4) * 64 + lane;
        f32x4 sacc[4];
        #pragma unroll
        for (int n = 0; n < 4; ++n) {
            float4 bb = bc[n * 64];
            f32x4 ci = {bb.x, bb.y, bb.z, bb.w};
            sacc[n] = MFMA(kb[n].b8, qa.b8, ci);   // S^T: col=i, rows=j
        }
        if (boundary) {
            int pi = regionOf(wh * 8 + (i_tok >> 3)) * 3 + regionOf(ww * 8 + (i_tok & 7));
            #pragma unroll
            for (int n = 0; n < 4; ++n)
                #pragma unroll
                for (int jj = 0; jj < 4; ++jj) {
                    int j = n * 16 + g * 4 + jj;
                    int pj = regionOf(wh * 8 + (j >> 3)) * 3 + regionOf(ww * 8 + (j & 7));
                    if (pi != pj) sacc[n][jj] -= MASK_L2E;
                }
        }
        // no-max exp2 (S bounded; masked -> exp2(-144) = 0)
        unsigned w0[4], w1[4];
        #pragma unroll
        for (int n = 0; n < 4; ++n) {
            float e0 = __builtin_exp2f(sacc[n][0]);
            float e1 = __builtin_exp2f(sacc[n][1]);
            float e2 = __builtin_exp2f(sacc[n][2]);
            float e3 = __builtin_exp2f(sacc[n][3]);
            w0[n] = pk2bf(e0, e1);
            w1[n] = pk2bf(e2, e3);
        }
        // write all 4 P-pairs (both K-halves), verified mapping
        #pragma unroll
        for (int n = 0; n < 4; ++n) {
            int wb = (n >> 1) * 64 + (((n & 1) * 2 + (g >> 1)) << 4) + ((g & 1) << 3);
            *(int2*)(slab + swz(prow, wb)) = make_int2(w0[n], w1[n]);
        }
        // single wait, two b128 reads, both PV MFMAs
        Frag pf0, pf1;
        pf0.i4 = *(const int4*)(slab + swz(prow, g * 16));
        pf1.i4 = *(const int4*)(slab + swz(prow, 64 + g * 16));
        f32x4 pv = {0.f, 0.f, 0.f, 0.f};
        pv = MFMA(va[0].b8, pf0.b8, pv);
        pv = MFMA(va[1].b8, pf1.b8, pv);

        float denom = __int_as_float(__builtin_amdgcn_ds_bpermute(dl, __float_as_int(pv[2])));
        float rinv  = __builtin_amdgcn_rcpf(denom);

        unsigned q01 = pk2bf(pv[0] * rinv, pv[1] * rinv);
        unsigned q23 = pk2bf(pv[2] * rinv, pv[3] * rinv);
        if (g < 2) {
            *(unsigned*)((char*)osb + swz(i_tok, h * 20 + g * 8 + 0)) = q01;
            *(unsigned*)((char*)osb + swz(i_tok, h * 20 + g * 8 + 4)) = q23;
        } else if (g == 2) {
            *(unsigned*)((char*)osb + swz(i_tok, h * 20 + 16)) = q01;  // d8,d9
        }
    }
}

// ---------------------------------------------------------------------------
// Prep: weight frags (bf16; Wq prescaled by scale*log2e) + C-frag bias table
// ---------------------------------------------------------------------------
__global__ void swin_prep(const float* __restrict__ qw,    // [60][180]
                          const float* __restrict__ pw,    // [60][60]
                          const float* __restrict__ bias,  // [225][6]
                          unsigned char* __restrict__ ws)
{
    int t = blockIdx.x * 256 + threadIdx.x;
    if (t < 1536) {                        // q/k A-frags: mt = h*2+type, f = mt*2+ks
        int lane = t & 63, f = t >> 6;
        int mt = f >> 1, ks = f & 1;
        int h = mt >> 1, type = mt & 1;
        int d = lane & 15, g8 = lane >> 4;
        unsigned short v8[8];
        #pragma unroll
        for (int jj = 0; jj < 8; ++jj) {
            int c = ks * 32 + g8 * 8 + jj;
            float wv = (d < 10 && c < 60) ? qw[c * 180 + type * 60 + h * 10 + d] : 0.f;
            if (type == 0) wv *= SCALE_L2E;      // fold softmax scale+log2e into Wq
            v8[jj] = f2bf(wv);
        }
        int4 p;
        p.x = v8[0] | (v8[1] << 16);  p.y = v8[2] | (v8[3] << 16);
        p.z = v8[4] | (v8[5] << 16);  p.w = v8[6] | (v8[7] << 16);
        *(int4*)(ws + WS_QKVF + t * 16) = p;
    } else if (t < 2304) {                 // v B-frags: f = h*2+ks; col=d, k=c
        int t2 = t - 1536;
        int lane = t2 & 63, f = t2 >> 6;
        int h = f >> 1, ks = f & 1;
        int d = lane & 15, g8 = lane >> 4;
        unsigned short v8[8];
        #pragma unroll
        for (int jj = 0; jj < 8; ++jj) {
            int c = ks * 32 + g8 * 8 + jj;
            v8[jj] = f2bf((d < 10 && c < 60) ? qw[c * 180 + 120 + h * 10 + d] : 0.f);
        }
        int4 p;
        p.x = v8[0] | (v8[1] << 16);  p.y = v8[2] | (v8[3] << 16);
        p.z = v8[4] | (v8[5] << 16);  p.w = v8[6] | (v8[7] << 16);
        *(int4*)(ws + WS_VF + t2 * 16) = p;
    } else if (t < 2816) {                 // proj^T A-frags
        int t2 = t - 2304;
        int lane = t2 & 63, fq = t2 >> 6;
        int m = fq >> 1, ks = fq & 1;
        int c = m * 16 + (lane & 15);
        int g8 = lane >> 4;
        unsigned short v8[8];
        #pragma unroll
        for (int jj = 0; jj < 8; ++jj) {
            int cc = ks * 32 + g8 * 8 + jj;
            v8[jj] = f2bf((c < 60 && cc < 60) ? pw[cc * 60 + c] : 0.f);
        }
        int4 p;
        p.x = v8[0] | (v8[1] << 16);  p.y = v8[2] | (v8[3] << 16);
        p.z = v8[4] | (v8[5] << 16);  p.w = v8[6] | (v8[7] << 16);
        *(int4*)(ws + WS_PROJF + t2 * 16) = p;
    } else if (t < 2816 + 24576) {         // bias C-frag table [6][4m][4n][64 lane][4 jj]
        int idx = t - 2816;
        int h = idx >> 12;
        int r = idx & 4095;
        int m = r >> 10;
        int n = (r >> 8) & 3;
        int lane = (r >> 2) & 63;
        int jj = r & 3;
        int i = m * 16 + (lane & 15);               // C col = i token
        int j = n * 16 + (lane >> 4) * 4 + jj;      // C row = j token
        int yi = i >> 3, xi = i & 7, yj = j >> 3, xj = j & 7;
        int ridx = (yi - yj + 7) * 15 + (xi - xj + 7);
        ((float*)(ws + WS_BIASC))[idx] = bias[ridx * 6 + h] * LOG2E;
    }
}

// ---------------------------------------------------------------------------
// Main fused kernel: one 256-thread block per window, 3 barriers, 31.5 KB LDS
// X loaded DIRECTLY global->registers (no phase-0 staging, no entry barrier).
// uni = P-slab only. Output overlays kall after block-wide K-frag hoist.
// ---------------------------------------------------------------------------
__global__ __launch_bounds__(256, 4)
void swin_mfma(const float* __restrict__ img,
               const float* __restrict__ pbias,   // [60]
               const unsigned char* __restrict__ ws,
               float* __restrict__ out)
{
    __shared__ __align__(16) unsigned short uni [64 * 64];  // P-slabs (128B rows)
    __shared__ __align__(16) unsigned short qall[64 * 64];  // packed-60 per tok
    __shared__ __align__(16) unsigned short kall[64 * 64];  // K; osb overlay in ph2
    __shared__ __align__(16) unsigned short vall[60 * 64];  // rows h*10+d (d<10)

    const int tid  = threadIdx.x;
    const int lane = tid & 63;
    const int wid  = __builtin_amdgcn_readfirstlane(tid >> 6);
    const int l15  = lane & 15;
    const int g    = lane >> 4;
    const int dl   = (32 + l15) << 2;         // bpermute lane for denominator

    const int bid = blockIdx.x;
    const int b   = bid / WNUM;
    const int wi  = bid - b * WNUM;
    const int wh  = wi / NWIN;
    const int ww  = wi - wh * NWIN;
    const bool boundary = (wh == NWIN - 1) || (ww == NWIN - 1);

    // ---- kall pad bytes 120..127 := 0 (read only in phase 3; two barriers
    //      separate this from its readers — no entry barrier needed) ---------
    if (tid < 128) {
        int row = tid >> 1, half = tid & 1;
        *(unsigned int*)((char*)kall + swz(row, 120 + half * 4)) = 0u;
    }

    // ---- phase 1: X direct global->regs (shift folded), then QKV^T ---------
    {
        Frag xb[4][2];
        #pragma unroll
        for (int n = 0; n < 4; ++n) {
            int tok = n * 16 + l15;
            int yi = tok >> 3, xi = tok & 7;
            int sh = wh * 8 + yi + 4; if (sh >= IMG) sh -= IMG;
            int sw = ww * 8 + xi + 4; if (sw >= IMG) sw -= IMG;
            const float* tp = img + ((size_t)(b * IMG + sh) * IMG + sw) * CDIM;
            #pragma unroll
            for (int ks = 0; ks < 2; ++ks) {
                int c0 = ks * 32 + g * 8;
                float4 va4 = *(const float4*)(tp + c0);
                float4 vb4 = *(const float4*)(tp + c0 + 4);
                unsigned p0 = pk2bf(va4.x, va4.y);
                unsigned p1 = pk2bf(va4.z, va4.w);
                unsigned p2 = pk2bf(vb4.x, vb4.y);
                unsigned p3 = pk2bf(vb4.z, vb4.w);
                if (c0 == 56) { p2 = 0u; p3 = 0u; }   // channels 60..63 := 0
                xb[n][ks].i4 = int4{(int)p0, (int)p1, (int)p2, (int)p3};
            }
        }

        const int4* wsq = (const int4*)(ws + WS_QKVF);
        #pragma unroll
        for (int kk = 0; kk < 3; ++kk) {
            int mt = wid + kk * 4;             // uniform
            int h = mt >> 1, type = mt & 1;
            Frag a0, a1;
            a0.i4 = wsq[(mt * 2 + 0) * 64 + lane];
            a1.i4 = wsq[(mt * 2 + 1) * 64 + lane];
            unsigned short* dst = type ? kall : qall;
            #pragma unroll
            for (int n = 0; n < 4; ++n) {
                f32x4 acc = {0.f, 0.f, 0.f, 0.f};
                acc = MFMA(a0.b8, xb[n][0].b8, acc);
                acc = MFMA(a1.b8, xb[n][1].b8, acc);
                int tok = n * 16 + l15;
                unsigned pk01 = pk2bf(acc[0], acc[1]);
                unsigned pk23 = pk2bf(acc[2], acc[3]);
                if (g < 2)
                    *(int2*)((char*)dst + swz(tok, h * 16 + g * 8)) = make_int2(pk01, pk23);
                else if (g == 2)
                    *(unsigned*)((char*)dst + swz(tok, 96 + h * 4)) = pk01;  // d8,d9
            }
        }
        // V untransposed-write: A = X (xb), B = Wv  -> C[tok][d]
        const int4* wsv = (const int4*)(ws + WS_VF);
        int nv = (wid < 2) ? 2 : 1;
        #pragma unroll 1
        for (int kk = 0; kk < nv; ++kk) {
            int hv = wid + kk * 4;             // covers h 0..5
            Frag b0, b1;
            b0.i4 = wsv[(hv * 2 + 0) * 64 + lane];
            b1.i4 = wsv[(hv * 2 + 1) * 64 + lane];
            #pragma unroll
            for (int n = 0; n < 4; ++n) {
                f32x4 acc = {0.f, 0.f, 0.f, 0.f};
                acc = MFMA(xb[n][0].b8, b0.b8, acc);
                acc = MFMA(xb[n][1].b8, b1.b8, acc);
                if (l15 < 10) {
                    *(int2*)((char*)vall + swz(hv * 10 + l15, n * 32 + g * 8)) =
                        make_int2(pk2bf(acc[0], acc[1]), pk2bf(acc[2], acc[3]));
                }
            }
        }
    }
    __syncthreads();

    // ---- phase 2: hoist all K frags, barrier, then attention (osb -> kall) -
    {
        char* slab = (char*)uni;               // P-slabs: rows wid*16 + l15
        const int prow = wid * 16 + l15;
        const float4* biasC = (const float4*)(ws + WS_BIASC);
        const int h0 = wid + (wid >> 1);       // first head of this wave
        const int h1 = h0 + 1;

        Frag kb0[4], kb1[4];
        #pragma unroll
        for (int n = 0; n < 4; ++n) {
            kb0[n].i4 = qk_frag(kall, n * 16 + l15, h0, g);
            kb1[n].i4 = qk_frag(kall, n * 16 + l15, h1, g);
        }
        __syncthreads();                       // all kall reads done block-wide

        if ((wid & 1) == 0) {
            attn_group<4>(h0, 0, kb0, lane, l15, g, dl, boundary, wh, ww,
                          qall, vall, kall, slab, prow, biasC);
            attn_group<2>(h1, 0, kb1, lane, l15, g, dl, boundary, wh, ww,
                          qall, vall, kall, slab, prow, biasC);
        } else {
            attn_group<2>(h0, 2, kb0, lane, l15, g, dl, boundary, wh, ww,
                          qall, vall, kall, slab, prow, biasC);
            attn_group<4>(h1, 0, kb1, lane, l15, g, dl, boundary, wh, ww,
                          qall, vall, kall, slab, prow, biasC);
        }
    }
    __syncthreads();

    // ---- phase 3: Y^T = Wp^T . O^T (osb = kall), float4 stores -------------
    {
        const int4* wsp = (const int4*)(ws + WS_PROJF);
        Frag a0, a1;
        a0.i4 = wsp[(wid * 2 + 0) * 64 + lane];
        a1.i4 = wsp[(wid * 2 + 1) * 64 + lane];
        int c0 = wid * 16 + g * 4;
        float4 pbv = (c0 < 60) ? *(const float4*)&pbias[c0] : float4{0.f, 0.f, 0.f, 0.f};
        #pragma unroll
        for (int n = 0; n < 4; ++n) {
            Frag b0, b1;
            b0.i4 = *(const int4*)((const char*)kall + swz(n * 16 + l15, g * 16));
            b1.i4 = *(const int4*)((const char*)kall + swz(n * 16 + l15, 64 + g * 16));
            f32x4 acc = {0.f, 0.f, 0.f, 0.f};
            acc = MFMA(a0.b8, b0.b8, acc);
            acc = MFMA(a1.b8, b1.b8, acc);
            if (c0 < 60) {
                int tok = n * 16 + l15;
                int yi = tok >> 3, xi = tok & 7;
                int sh = wh * 8 + yi + 4; if (sh >= IMG) sh -= IMG;
                int sw = ww * 8 + xi + 4; if (sw >= IMG) sw -= IMG;
                float4 o = {acc[0] + pbv.x, acc[1] + pbv.y, acc[2] + pbv.z, acc[3] + pbv.w};
                *(float4*)&out[((b * IMG + sh) * IMG + sw) * CDIM + c0] = o;
            }
        }
    }
}

extern "C" void kernel_launch(void* const* d_in, const int* in_sizes, int n_in,
                              void* d_out, int out_size, void* d_ws, size_t ws_size,
                              hipStream_t stream) {
    const float* img  = (const float*)d_in[0];
    const float* qw   = (const float*)d_in[1];
    const float* bias = (const float*)d_in[2];
    const float* pw   = (const float*)d_in[3];
    const float* pb   = (const float*)d_in[4];
    float* out = (float*)d_out;

    swin_prep<<<107, 256, 0, stream>>>(qw, pw, bias, (unsigned char*)d_ws);
    swin_mfma<<<4 * WNUM, 256, 0, stream>>>(img, pb,
                                            (const unsigned char*)d_ws, out);
}

// Round 18
// 161.372 us; speedup vs baseline: 1.0483x; 1.0483x over previous
//
#include <hip/hip_runtime.h>
#include <hip/hip_bf16.h>

#define IMG    384
#define CDIM   60
#define NWIN   48
#define WNUM   (NWIN * NWIN)   // 2304

typedef short  bf16x8 __attribute__((ext_vector_type(8)));
typedef float  f32x4  __attribute__((ext_vector_type(4)));
union Frag { int4 i4; bf16x8 b8; };

#define MFMA(a, b, c) __builtin_amdgcn_mfma_f32_16x16x32_bf16((a), (b), (c), 0, 0, 0)

// d_ws layout
#define WS_QKVF  0        // 12 qk mtiles x 2 ks x 1KB = 24576 (A-frags; Wq pre-scaled)
#define WS_VF    24576    // 6 heads x 2 ks x 1KB      = 12288 (B-frags)
#define WS_PROJF 36864    // 4 x 2 x 1KB               = 8192  (A-frags)
#define WS_BIASC 45056    // [6][4][4][64] f32x4 C-frag bias (prescaled log2e) = 98304

#define SCALE_L2E (0.31622776601683794f * 1.4426950408889634f)  // 1/sqrt(10)*log2(e)
#define MASK_L2E  144.26950408889634f                            // 100*log2(e)
#define LOG2E     1.4426950408889634f

__device__ __forceinline__ unsigned short f2bf(float f) {
    unsigned int u = __float_as_uint(f);
    unsigned int r = u + 0x7fffu + ((u >> 16) & 1u);
    return (unsigned short)(r >> 16);
}
__device__ __forceinline__ unsigned int pk2bf(float a, float b) {
    union { __hip_bfloat162 h; unsigned int u; } c;
    c.h = __float22bfloat162_rn(float2{a, b});
    return c.u;
}
__device__ __forceinline__ int regionOf(int x) {
    return (x < IMG - 8) ? 0 : ((x < IMG - 4) ? 1 : 2);
}
// all LDS buffers: 128B rows, XOR swizzle on byte bit 4 keyed by row&7
__device__ __forceinline__ int swz(int row, int byteoff) {
    return (row * 128 + byteoff) ^ ((row & 7) << 4);
}
// q/k packed row: [6 heads x 16B (d0-7)] at h*16, [6 x 4B (d8,d9)] at 96+h*4
__device__ __forceinline__ int4 qk_frag(const unsigned short* buf, int tok, int h, int g) {
    if (g == 0) return *(const int4*)((const char*)buf + swz(tok, h * 16));
    if (g == 1) {
        int v = *(const int*)((const char*)buf + swz(tok, 96 + h * 4));
        return int4{v, 0, 0, 0};
    }
    return int4{0, 0, 0, 0};
}

// ---------------------------------------------------------------------------
// Attention head-group: MC m-tiles of head h. Full-width P slab: write all 4
// P-pairs (both K-halves) -> one wait -> 2 b128 reads -> both PV MFMAs.
// Denominator via ones-row (C row 10) + single ds_bpermute (R10-verified).
// Bias enters as the QK MFMA C-initializer.
// ---------------------------------------------------------------------------
template<int MC>
__device__ __forceinline__ void attn_group(
    int h, int m0, const Frag (&kb)[4],
    int lane, int l15, int g, int dl, bool boundary, int wh, int ww,
    const unsigned short* qall, const unsigned short* vall,
    unsigned short* osb,            // = kall region (overlay)
    char* slab, int prow, const float4* biasC)
{
    Frag va[2];
    int vrow = (l15 < 10) ? h * 10 + l15 : 60;     // row 60 = ones (denominator)
    #pragma unroll
    for (int ks = 0; ks < 2; ++ks)
        va[ks].i4 = *(const int4*)((const char*)vall + swz(vrow, ks * 64 + g * 16));

    #pragma unroll
    for (int mm = 0; mm < MC; ++mm) {
        int m = m0 + mm;
        int i_tok = m * 16 + l15;
        Frag qa;
        qa.i4 = qk_frag(qall, i_tok, h, g);

        // S^T with C = bias^T (prescaled by log2e; q prescaled by scale*log2e)
        const float4* bc = biasC + (h * 16 + m * 4) * 64 + lane;
        f32x4 sacc[4];
        #pragma unroll
        for (int n = 0; n < 4; ++n) {
            float4 bb = bc[n * 64];
            f32x4 ci = {bb.x, bb.y, bb.z, bb.w};
            sacc[n] = MFMA(kb[n].b8, qa.b8, ci);   // S^T: col=i, rows=j
        }
        if (boundary) {
            int pi = regionOf(wh * 8 + (i_tok >> 3)) * 3 + regionOf(ww * 8 + (i_tok & 7));
            #pragma unroll
            for (int n = 0; n < 4; ++n)
                #pragma unroll
                for (int jj = 0; jj < 4; ++jj) {
                    int j = n * 16 + g * 4 + jj;
                    int pj = regionOf(wh * 8 + (j >> 3)) * 3 + regionOf(ww * 8 + (j & 7));
                    if (pi != pj) sacc[n][jj] -= MASK_L2E;
                }
        }
        // no-max exp2 (S bounded; masked -> exp2(-144) = 0)
        unsigned w0[4], w1[4];
        #pragma unroll
        for (int n = 0; n < 4; ++n) {
            float e0 = __builtin_exp2f(sacc[n][0]);
            float e1 = __builtin_exp2f(sacc[n][1]);
            float e2 = __builtin_exp2f(sacc[n][2]);
            float e3 = __builtin_exp2f(sacc[n][3]);
            w0[n] = pk2bf(e0, e1);
            w1[n] = pk2bf(e2, e3);
        }
        // write all 4 P-pairs (both K-halves), verified mapping
        #pragma unroll
        for (int n = 0; n < 4; ++n) {
            int wb = (n >> 1) * 64 + (((n & 1) * 2 + (g >> 1)) << 4) + ((g & 1) << 3);
            *(int2*)(slab + swz(prow, wb)) = make_int2(w0[n], w1[n]);
        }
        // single wait, two b128 reads, both PV MFMAs
        Frag pf0, pf1;
        pf0.i4 = *(const int4*)(slab + swz(prow, g * 16));
        pf1.i4 = *(const int4*)(slab + swz(prow, 64 + g * 16));
        f32x4 pv = {0.f, 0.f, 0.f, 0.f};
        pv = MFMA(va[0].b8, pf0.b8, pv);
        pv = MFMA(va[1].b8, pf1.b8, pv);

        float denom = __int_as_float(__builtin_amdgcn_ds_bpermute(dl, __float_as_int(pv[2])));
        float rinv  = __builtin_amdgcn_rcpf(denom);

        unsigned q01 = pk2bf(pv[0] * rinv, pv[1] * rinv);
        unsigned q23 = pk2bf(pv[2] * rinv, pv[3] * rinv);
        if (g < 2) {
            *(unsigned*)((char*)osb + swz(i_tok, h * 20 + g * 8 + 0)) = q01;
            *(unsigned*)((char*)osb + swz(i_tok, h * 20 + g * 8 + 4)) = q23;
        } else if (g == 2) {
            *(unsigned*)((char*)osb + swz(i_tok, h * 20 + 16)) = q01;  // d8,d9
        }
    }
}

// ---------------------------------------------------------------------------
// Prep: weight frags (bf16; Wq prescaled by scale*log2e) + C-frag bias table
// ---------------------------------------------------------------------------
__global__ void swin_prep(const float* __restrict__ qw,    // [60][180]
                          const float* __restrict__ pw,    // [60][60]
                          const float* __restrict__ bias,  // [225][6]
                          unsigned char* __restrict__ ws)
{
    int t = blockIdx.x * 256 + threadIdx.x;
    if (t < 1536) {                        // q/k A-frags: mt = h*2+type, f = mt*2+ks
        int lane = t & 63, f = t >> 6;
        int mt = f >> 1, ks = f & 1;
        int h = mt >> 1, type = mt & 1;
        int d = lane & 15, g8 = lane >> 4;
        unsigned short v8[8];
        #pragma unroll
        for (int jj = 0; jj < 8; ++jj) {
            int c = ks * 32 + g8 * 8 + jj;
            float wv = (d < 10 && c < 60) ? qw[c * 180 + type * 60 + h * 10 + d] : 0.f;
            if (type == 0) wv *= SCALE_L2E;      // fold softmax scale+log2e into Wq
            v8[jj] = f2bf(wv);
        }
        int4 p;
        p.x = v8[0] | (v8[1] << 16);  p.y = v8[2] | (v8[3] << 16);
        p.z = v8[4] | (v8[5] << 16);  p.w = v8[6] | (v8[7] << 16);
        *(int4*)(ws + WS_QKVF + t * 16) = p;
    } else if (t < 2304) {                 // v B-frags: f = h*2+ks; col=d, k=c
        int t2 = t - 1536;
        int lane = t2 & 63, f = t2 >> 6;
        int h = f >> 1, ks = f & 1;
        int d = lane & 15, g8 = lane >> 4;
        unsigned short v8[8];
        #pragma unroll
        for (int jj = 0; jj < 8; ++jj) {
            int c = ks * 32 + g8 * 8 + jj;
            v8[jj] = f2bf((d < 10 && c < 60) ? qw[c * 180 + 120 + h * 10 + d] : 0.f);
        }
        int4 p;
        p.x = v8[0] | (v8[1] << 16);  p.y = v8[2] | (v8[3] << 16);
        p.z = v8[4] | (v8[5] << 16);  p.w = v8[6] | (v8[7] << 16);
        *(int4*)(ws + WS_VF + t2 * 16) = p;
    } else if (t < 2816) {                 // proj^T A-frags
        int t2 = t - 2304;
        int lane = t2 & 63, fq = t2 >> 6;
        int m = fq >> 1, ks = fq & 1;
        int c = m * 16 + (lane & 15);
        int g8 = lane >> 4;
        unsigned short v8[8];
        #pragma unroll
        for (int jj = 0; jj < 8; ++jj) {
            int cc = ks * 32 + g8 * 8 + jj;
            v8[jj] = f2bf((c < 60 && cc < 60) ? pw[cc * 60 + c] : 0.f);
        }
        int4 p;
        p.x = v8[0] | (v8[1] << 16);  p.y = v8[2] | (v8[3] << 16);
        p.z = v8[4] | (v8[5] << 16);  p.w = v8[6] | (v8[7] << 16);
        *(int4*)(ws + WS_PROJF + t2 * 16) = p;
    } else if (t < 2816 + 24576) {         // bias C-frag table [6][4m][4n][64 lane][4 jj]
        int idx = t - 2816;
        int h = idx >> 12;
        int r = idx & 4095;
        int m = r >> 10;
        int n = (r >> 8) & 3;
        int lane = (r >> 2) & 63;
        int jj = r & 3;
        int i = m * 16 + (lane & 15);               // C col = i token
        int j = n * 16 + (lane >> 4) * 4 + jj;      // C row = j token
        int yi = i >> 3, xi = i & 7, yj = j >> 3, xj = j & 7;
        int ridx = (yi - yj + 7) * 15 + (xi - xj + 7);
        ((float*)(ws + WS_BIASC))[idx] = bias[ridx * 6 + h] * LOG2E;
    }
}

// ---------------------------------------------------------------------------
// Main fused kernel: one 256-thread block per window, 4 barriers, 32 KB LDS
// Output overlays kall after block-wide K-frag hoist; P slab = uni (128B rows).
// ---------------------------------------------------------------------------
__global__ __launch_bounds__(256, 4)
void swin_mfma(const float* __restrict__ img,
               const float* __restrict__ pbias,   // [60]
               const unsigned char* __restrict__ ws,
               float* __restrict__ out)
{
    __shared__ __align__(16) unsigned short uni [64 * 64];  // xb / P-slabs (128B rows)
    __shared__ __align__(16) unsigned short qall[64 * 64];  // packed-60 per tok
    __shared__ __align__(16) unsigned short kall[64 * 64];  // K; osb overlay in ph2
    __shared__ __align__(16) unsigned short vall[61 * 64];  // rows h*10+d; row 60 = ones

    const int tid  = threadIdx.x;
    const int lane = tid & 63;
    const int wid  = __builtin_amdgcn_readfirstlane(tid >> 6);
    const int l15  = lane & 15;
    const int g    = lane >> 4;
    const int dl   = (32 + l15) << 2;         // bpermute lane for denominator

    const int bid = blockIdx.x;
    const int b   = bid / WNUM;
    const int wi  = bid - b * WNUM;
    const int wh  = wi / NWIN;
    const int ww  = wi - wh * NWIN;
    const bool boundary = (wh == NWIN - 1) || (ww == NWIN - 1);

    // ---- phase 0: load window (shift folded), token=lane, chunk=wid --------
    {
        int tok = lane;
        int yi = tok >> 3, xi = tok & 7;
        int sh = wh * 8 + yi + 4; if (sh >= IMG) sh -= IMG;
        int sw = ww * 8 + xi + 4; if (sw >= IMG) sw -= IMG;
        const float* src = img + ((size_t)(b * IMG + sh) * IMG + sw) * CDIM;
        #pragma unroll
        for (int it = 0; it < 4; ++it) {
            int cg = wid + it * 4;
            if (cg < 15) {
                float4 v = *(const float4*)(src + cg * 4);
                *(int2*)((char*)uni + swz(tok, cg * 8)) =
                    make_int2(pk2bf(v.x, v.y), pk2bf(v.z, v.w));
            } else {
                *(int2*)((char*)uni + swz(tok, 120)) = make_int2(0, 0);
            }
        }
    }
    if (tid < 128) {                           // kall logical bytes 120..127 := 0
        int row = tid >> 1, half = tid & 1;    // (osb pad for phase-3 B-frags)
        *(unsigned int*)((char*)kall + swz(row, 120 + half * 4)) = 0u;
    }
    if (tid < 32) {                            // vall ones-row (row 60)
        *(unsigned int*)((char*)vall + swz(60, tid * 4)) = 0x3F803F80u;
    }
    __syncthreads();

    // ---- phase 1: QKV^T (12 q/k mtiles: 3/wave; 6 v heads: wave<2 gets 2) --
    {
        Frag xb[4][2];
        #pragma unroll
        for (int n = 0; n < 4; ++n)
            #pragma unroll
            for (int ks = 0; ks < 2; ++ks)
                xb[n][ks].i4 = *(const int4*)((const char*)uni + swz(n * 16 + l15, ks * 64 + g * 16));

        const int4* wsq = (const int4*)(ws + WS_QKVF);
        #pragma unroll
        for (int kk = 0; kk < 3; ++kk) {
            int mt = wid + kk * 4;             // uniform
            int h = mt >> 1, type = mt & 1;
            Frag a0, a1;
            a0.i4 = wsq[(mt * 2 + 0) * 64 + lane];
            a1.i4 = wsq[(mt * 2 + 1) * 64 + lane];
            unsigned short* dst = type ? kall : qall;
            #pragma unroll
            for (int n = 0; n < 4; ++n) {
                f32x4 acc = {0.f, 0.f, 0.f, 0.f};
                acc = MFMA(a0.b8, xb[n][0].b8, acc);
                acc = MFMA(a1.b8, xb[n][1].b8, acc);
                int tok = n * 16 + l15;
                unsigned pk01 = pk2bf(acc[0], acc[1]);
                unsigned pk23 = pk2bf(acc[2], acc[3]);
                if (g < 2)
                    *(int2*)((char*)dst + swz(tok, h * 16 + g * 8)) = make_int2(pk01, pk23);
                else if (g == 2)
                    *(unsigned*)((char*)dst + swz(tok, 96 + h * 4)) = pk01;  // d8,d9
            }
        }
        // V untransposed-write: A = X (xb), B = Wv  -> C[tok][d]
        const int4* wsv = (const int4*)(ws + WS_VF);
        int nv = (wid < 2) ? 2 : 1;
        #pragma unroll 1
        for (int kk = 0; kk < nv; ++kk) {
            int hv = wid + kk * 4;             // covers h 0..5
            Frag b0, b1;
            b0.i4 = wsv[(hv * 2 + 0) * 64 + lane];
            b1.i4 = wsv[(hv * 2 + 1) * 64 + lane];
            #pragma unroll
            for (int n = 0; n < 4; ++n) {
                f32x4 acc = {0.f, 0.f, 0.f, 0.f};
                acc = MFMA(xb[n][0].b8, b0.b8, acc);
                acc = MFMA(xb[n][1].b8, b1.b8, acc);
                if (l15 < 10) {
                    *(int2*)((char*)vall + swz(hv * 10 + l15, n * 32 + g * 8)) =
                        make_int2(pk2bf(acc[0], acc[1]), pk2bf(acc[2], acc[3]));
                }
            }
        }
    }
    __syncthreads();

    // ---- phase 2: hoist all K frags, barrier, then attention (osb -> kall) -
    {
        char* slab = (char*)uni;               // P-slabs: rows wid*16 + l15
        const int prow = wid * 16 + l15;
        const float4* biasC = (const float4*)(ws + WS_BIASC);
        const int h0 = wid + (wid >> 1);       // first head of this wave
        const int h1 = h0 + 1;

        Frag kb0[4], kb1[4];
        #pragma unroll
        for (int n = 0; n < 4; ++n) {
            kb0[n].i4 = qk_frag(kall, n * 16 + l15, h0, g);
            kb1[n].i4 = qk_frag(kall, n * 16 + l15, h1, g);
        }
        __syncthreads();                       // all kall reads done block-wide

        if ((wid & 1) == 0) {
            attn_group<4>(h0, 0, kb0, lane, l15, g, dl, boundary, wh, ww,
                          qall, vall, kall, slab, prow, biasC);
            attn_group<2>(h1, 0, kb1, lane, l15, g, dl, boundary, wh, ww,
                          qall, vall, kall, slab, prow, biasC);
        } else {
            attn_group<2>(h0, 2, kb0, lane, l15, g, dl, boundary, wh, ww,
                          qall, vall, kall, slab, prow, biasC);
            attn_group<4>(h1, 0, kb1, lane, l15, g, dl, boundary, wh, ww,
                          qall, vall, kall, slab, prow, biasC);
        }
    }
    __syncthreads();

    // ---- phase 3: Y^T = Wp^T . O^T (osb = kall), float4 stores -------------
    {
        const int4* wsp = (const int4*)(ws + WS_PROJF);
        Frag a0, a1;
        a0.i4 = wsp[(wid * 2 + 0) * 64 + lane];
        a1.i4 = wsp[(wid * 2 + 1) * 64 + lane];
        int c0 = wid * 16 + g * 4;
        float4 pbv = (c0 < 60) ? *(const float4*)&pbias[c0] : float4{0.f, 0.f, 0.f, 0.f};
        #pragma unroll
        for (int n = 0; n < 4; ++n) {
            Frag b0, b1;
            b0.i4 = *(const int4*)((const char*)kall + swz(n * 16 + l15, g * 16));
            b1.i4 = *(const int4*)((const char*)kall + swz(n * 16 + l15, 64 + g * 16));
            f32x4 acc = {0.f, 0.f, 0.f, 0.f};
            acc = MFMA(a0.b8, b0.b8, acc);
            acc = MFMA(a1.b8, b1.b8, acc);
            if (c0 < 60) {
                int tok = n * 16 + l15;
                int yi = tok >> 3, xi = tok & 7;
                int sh = wh * 8 + yi + 4; if (sh >= IMG) sh -= IMG;
                int sw = ww * 8 + xi + 4; if (sw >= IMG) sw -= IMG;
                float4 o = {acc[0] + pbv.x, acc[1] + pbv.y, acc[2] + pbv.z, acc[3] + pbv.w};
                *(float4*)&out[((b * IMG + sh) * IMG + sw) * CDIM + c0] = o;
            }
        }
    }
}

extern "C" void kernel_launch(void* const* d_in, const int* in_sizes, int n_in,
                              void* d_out, int out_size, void* d_ws, size_t ws_size,
                              hipStream_t stream) {
    const float* img  = (const float*)d_in[0];
    const float* qw   = (const float*)d_in[1];
    const float* bias = (const float*)d_in[2];
    const float* pw   = (const float*)d_in[3];
    const float* pb   = (const float*)d_in[4];
    float* out = (float*)d_out;

    swin_prep<<<107, 256, 0, stream>>>(qw, pw, bias, (unsigned char*)d_ws);
    swin_mfma<<<4 * WNUM, 256, 0, stream>>>(img, pb,
                                            (const unsigned char*)d_ws, out);
}